// Round 8
// baseline (733.555 us; speedup 1.0000x reference)
//
#include <hip/hip_runtime.h>
#include <hip/hip_bf16.h>

// ---------------------------------------------------------------------------
// SupplyChainGNN: 3-layer GCN (PyG GCNConv semantics) + global mean pool.
//   deg[i] = 1 + indeg(i);  dinv = rsqrt(deg)
//   GEMM (bf16 MFMA) folds dinv into its output: h' = dinv[row]*(A@W) (bf16)
//   agg:  out[i] = dinv[i]*( sum_{e: dst=i} h'[src] + h'[i] ) + b  (+ReLU)
// CSR (by dst) rebuilt on-device every call (workspace is re-poisoned).
//
// R1: fill range-partitioned (blockIdx%8 ~ XCD) -> full-line col[] writes.
// R2: H stored bf16 + deep gather pipelining.
// R3: GEMMs -> mfma_f32_16x16x32_bf16, W frags in VGPRs, A direct-global.
// R5: (a) nt-loads for src/dst/col streams (stop evicting L2 reuse-targets);
//     (b) feature-SLICED h layout: Hs[slice][node][16], slice r gathered only
//         by blocks blockIdx&7==r -> per-XCD gather footprint 3.2MB fits L2;
//     (c) dinv[src] folded into GEMM epilogue -> no per-edge dinv gather/mul.
// R6/R7: identical resubmits (GPUAcquisitionTimeout both rounds; no data).
// ---------------------------------------------------------------------------

typedef unsigned int uint32;
typedef short short8 __attribute__((ext_vector_type(8)));
typedef float f32x4 __attribute__((ext_vector_type(4)));

static __device__ __forceinline__ unsigned short f2bf(float f) {
    uint32 u = __float_as_uint(f);
    return (unsigned short)((u + 0x7fffu + ((u >> 16) & 1u)) >> 16);  // RNE
}
static __device__ __forceinline__ float bf2f_lo(uint32 u) {
    return __uint_as_float(u << 16);
}
static __device__ __forceinline__ float bf2f_hi(uint32 u) {
    return __uint_as_float(u & 0xffff0000u);
}

__global__ __launch_bounds__(256) void initdeg_k(int* deg, int M) {
    int i = blockIdx.x * 256 + threadIdx.x;
    if (i < M) deg[i] = 1;  // self loop
}

__global__ __launch_bounds__(256) void count_k(const int* __restrict__ dst, int E,
                                               int* __restrict__ deg) {
    int e = blockIdx.x * 256 + threadIdx.x;
    if (e < E) atomicAdd(&deg[__builtin_nontemporal_load(&dst[e])], 1);
}

__global__ __launch_bounds__(256) void mkdinv_k(const int* __restrict__ deg,
                                                float* __restrict__ dinv, int M) {
    int i = blockIdx.x * 256 + threadIdx.x;
    if (i < M) dinv[i] = rsqrtf((float)deg[i]);
}

// ---- block-scan of edge counts (deg-1) to build rowptr --------------------
__global__ __launch_bounds__(256) void scan1_k(const int* __restrict__ deg, int M,
                                               int* __restrict__ blksum) {
    __shared__ int sh[256];
    int i = blockIdx.x * 256 + threadIdx.x;
    int v = (i < M) ? deg[i] - 1 : 0;
    sh[threadIdx.x] = v;
    __syncthreads();
    for (int o = 128; o > 0; o >>= 1) {
        if (threadIdx.x < o) sh[threadIdx.x] += sh[threadIdx.x + o];
        __syncthreads();
    }
    if (threadIdx.x == 0) blksum[blockIdx.x] = sh[0];
}

__global__ __launch_bounds__(512) void scan2_k(int* __restrict__ blksum, int nb) {
    __shared__ int sh[512];
    int tid = threadIdx.x;
    int v = (tid < nb) ? blksum[tid] : 0;
    sh[tid] = v;
    __syncthreads();
    for (int o = 1; o < 512; o <<= 1) {
        int t = (tid >= o) ? sh[tid - o] : 0;
        __syncthreads();
        sh[tid] += t;
        __syncthreads();
    }
    if (tid < nb) blksum[tid] = sh[tid] - v;  // exclusive
}

__global__ __launch_bounds__(256) void scan3_k(const int* __restrict__ deg, int M,
                                               const int* __restrict__ blksum,
                                               int* __restrict__ rowptr,
                                               int* __restrict__ cursor) {
    __shared__ int sh[256];
    int tid = threadIdx.x;
    int i = blockIdx.x * 256 + tid;
    int v = (i < M) ? deg[i] - 1 : 0;
    sh[tid] = v;
    __syncthreads();
    for (int o = 1; o < 256; o <<= 1) {
        int t = (tid >= o) ? sh[tid - o] : 0;
        __syncthreads();
        sh[tid] += t;
        __syncthreads();
    }
    int excl = sh[tid] - v + blksum[blockIdx.x];
    if (i < M) {
        rowptr[i] = excl;
        cursor[i] = excl;
    }
    if (i == M - 1) rowptr[M] = excl + v;
}

// ---- CSR slot fill, dst-range partitioned; nt edge reads ------------------
#define FILL_CHUNK 4096
__global__ __launch_bounds__(256) void fill_rp_k(const int* __restrict__ src,
                                                 const int* __restrict__ dst,
                                                 int E, int M,
                                                 int* __restrict__ cursor,
                                                 int* __restrict__ col) {
    const int r = blockIdx.x & 7;
    const int chunk = blockIdx.x >> 3;
    const int lo = (int)(((long long)r * M) >> 3);
    const int hi = (int)(((long long)(r + 1) * M) >> 3);
    const int base = chunk * FILL_CHUNK;
    const int end = min(E, base + FILL_CHUNK);
    for (int e = base + (int)threadIdx.x; e < end; e += 256) {
        int d = __builtin_nontemporal_load(&dst[e]);
        int s = __builtin_nontemporal_load(&src[e]);
        if (d >= lo && d < hi) {
            int slot = atomicAdd(&cursor[d], 1);
            col[slot] = s;
        }
    }
}

// ---- f32 x -> bf16 sliced layout Xs[k/16][node][16] -----------------------
__global__ __launch_bounds__(256) void cvt_k(const float* __restrict__ x,
                                             unsigned short* __restrict__ o,
                                             int M, int n8) {
    int i = blockIdx.x * 256 + threadIdx.x;
    if (i >= n8) return;
    const float4* xp = (const float4*)x + (size_t)i * 2;
    float4 a = xp[0], b = xp[1];
    union { unsigned short us[8]; uint4 v; } u;
    u.us[0] = f2bf(a.x); u.us[1] = f2bf(a.y); u.us[2] = f2bf(a.z); u.us[3] = f2bf(a.w);
    u.us[4] = f2bf(b.x); u.us[5] = f2bf(b.y); u.us[6] = f2bf(b.z); u.us[7] = f2bf(b.w);
    int node = i >> 4;
    int k0 = (i & 15) * 8;
    size_t di = ((size_t)(k0 >> 4) * M + node) * 16 + (k0 & 15);
    *(uint4*)&o[di] = u.v;
}

// ---- W[128][N] f32 -> Wt[N][128] bf16 (transpose + convert) ---------------
__global__ __launch_bounds__(256) void wt_k(const float* __restrict__ W,
                                            unsigned short* __restrict__ Wt,
                                            int N) {
    int idx = blockIdx.x * 256 + threadIdx.x;
    if (idx >= N * 128) return;
    int n = idx >> 7, k = idx & 127;
    Wt[idx] = f2bf(W[k * N + n]);
}

// ---- MFMA GEMM: C = dinv[row] * (A @ W), A sliced-16, C sliced or row-major
// frag: lane r=l&15 (row/col), g=l>>4; elem j of (g,s) <-> k=32s+8g+j.
// A sliced: k -> slice q=2s+(g>>1), offset (g&1)*8+j.
// C/D (m89): col=l&15, row=4*(l>>4)+reg.
template <int NT, bool SOUT>  // NT 16-col tiles; N=16*NT
__global__ __launch_bounds__(256) void mgemm_k(const unsigned short* __restrict__ A,
                                               const unsigned short* __restrict__ Wt,
                                               const float* __restrict__ dinv,
                                               unsigned short* __restrict__ C,
                                               int M, int nstrips) {
    constexpr int N = NT * 16;
    const int lane = threadIdx.x & 63;
    const int wid = threadIdx.x >> 6;
    const int r = lane & 15;
    const int g = lane >> 4;

    short8 wf[NT][4];
#pragma unroll
    for (int t = 0; t < NT; t++)
#pragma unroll
        for (int s = 0; s < 4; s++)
            wf[t][s] = *(const short8*)&Wt[(size_t)(t * 16 + r) * 128 + s * 32 + g * 8];

    const int stride = gridDim.x * 4;
    for (int strip = blockIdx.x * 4 + wid; strip < nstrips; strip += stride) {
        const int R = strip * 16;
        const int ar = min(R + r, M - 1);
        short8 af[4];
#pragma unroll
        for (int s = 0; s < 4; s++) {
            const int q = 2 * s + (g >> 1);
            af[s] = *(const short8*)&A[((size_t)q * M + ar) * 16 + (g & 1) * 8];
        }
        f32x4 acc[NT];
#pragma unroll
        for (int t = 0; t < NT; t++) acc[t] = (f32x4){0.f, 0.f, 0.f, 0.f};
#pragma unroll
        for (int s = 0; s < 4; s++)
#pragma unroll
            for (int t = 0; t < NT; t++)
                acc[t] = __builtin_amdgcn_mfma_f32_16x16x32_bf16(
                    af[s], wf[t][s], acc[t], 0, 0, 0);
#pragma unroll
        for (int j = 0; j < 4; j++) {
            int row = R + 4 * g + j;
            if (row < M) {
                float dv = dinv[row];
#pragma unroll
                for (int t = 0; t < NT; t++) {
                    unsigned short v = f2bf(dv * acc[t][j]);
                    if (SOUT)
                        C[((size_t)t * M + row) * 16 + r] = v;
                    else
                        C[(size_t)row * N + t * 16 + r] = v;
                }
            }
        }
    }
}

// ---- sliced aggregation, F=128: blockIdx&7 = slice (XCD-affine) -----------
// 8 lanes per node (uint32 = 2 bf16 feats each); slice footprint 3.2MB -> L2.
__global__ __launch_bounds__(256) void agg128s_k(const unsigned short* __restrict__ Hs,
                                                 const int* __restrict__ rowptr,
                                                 const int* __restrict__ col,
                                                 const float* __restrict__ dinv,
                                                 const float* __restrict__ bias,
                                                 unsigned short* __restrict__ Os,
                                                 int M, int relu) {
    const int slice = blockIdx.x & 7;
    const int nb = blockIdx.x >> 3;
    const int lane = threadIdx.x & 63;
    const int wid = threadIdx.x >> 6;
    const int grp = lane >> 3;
    const int j = lane & 7;
    const int node = nb * 32 + wid * 8 + grp;
    if (node >= M) return;
    const uint32* H = (const uint32*)Hs + (size_t)slice * M * 8;
    uint32* O = (uint32*)Os + (size_t)slice * M * 8;

    float a0, a1;
    {
        uint32 u = H[(size_t)node * 8 + j];  // self term (h' includes dinv)
        a0 = bf2f_lo(u); a1 = bf2f_hi(u);
    }
    const int s = rowptr[node], e = rowptr[node + 1];
    int i = s;
    for (; i + 4 <= e; i += 4) {
        int c0 = __builtin_nontemporal_load(&col[i]);
        int c1 = __builtin_nontemporal_load(&col[i + 1]);
        int c2 = __builtin_nontemporal_load(&col[i + 2]);
        int c3 = __builtin_nontemporal_load(&col[i + 3]);
        uint32 u0 = H[(size_t)c0 * 8 + j];
        uint32 u1 = H[(size_t)c1 * 8 + j];
        uint32 u2 = H[(size_t)c2 * 8 + j];
        uint32 u3 = H[(size_t)c3 * 8 + j];
        a0 += bf2f_lo(u0); a1 += bf2f_hi(u0);
        a0 += bf2f_lo(u1); a1 += bf2f_hi(u1);
        a0 += bf2f_lo(u2); a1 += bf2f_hi(u2);
        a0 += bf2f_lo(u3); a1 += bf2f_hi(u3);
    }
    for (; i < e; i++) {
        int c0 = __builtin_nontemporal_load(&col[i]);
        uint32 u0 = H[(size_t)c0 * 8 + j];
        a0 += bf2f_lo(u0); a1 += bf2f_hi(u0);
    }
    float dv = dinv[node];
    float2 bv = *(const float2*)&bias[slice * 16 + j * 2];
    float ox = fmaf(dv, a0, bv.x), oy = fmaf(dv, a1, bv.y);
    if (relu) { ox = fmaxf(ox, 0.f); oy = fmaxf(oy, 0.f); }
    uint32 pk = (uint32)f2bf(ox) | ((uint32)f2bf(oy) << 16);
    __builtin_nontemporal_store(pk, &O[(size_t)node * 8 + j]);
}

// ---- aggregation, F=32 (h' bf16 row-major [M,32]) -> f32 out --------------
__global__ __launch_bounds__(256) void agg32_k(const unsigned short* __restrict__ Hb,
                                               const int* __restrict__ rowptr,
                                               const int* __restrict__ col,
                                               const float* __restrict__ dinv,
                                               const float* __restrict__ bias,
                                               float* __restrict__ out, int M) {
    int node = blockIdx.x * 4 + (threadIdx.x >> 6);
    if (node >= M) return;
    int lane = threadIdx.x & 63;
    int f = lane & 31;
    int half = lane >> 5;
    float acc = 0.f;
    if (!half)
        acc = __uint_as_float(((uint32)Hb[(size_t)node * 32 + f]) << 16);  // self
    const int s = rowptr[node], e = rowptr[node + 1];
    int i = s + half;
    for (; i + 6 < e; i += 8) {
        int s0 = __builtin_nontemporal_load(&col[i]);
        int s1 = __builtin_nontemporal_load(&col[i + 2]);
        int s2 = __builtin_nontemporal_load(&col[i + 4]);
        int s3 = __builtin_nontemporal_load(&col[i + 6]);
        float h0 = __uint_as_float(((uint32)Hb[(size_t)s0 * 32 + f]) << 16);
        float h1 = __uint_as_float(((uint32)Hb[(size_t)s1 * 32 + f]) << 16);
        float h2 = __uint_as_float(((uint32)Hb[(size_t)s2 * 32 + f]) << 16);
        float h3 = __uint_as_float(((uint32)Hb[(size_t)s3 * 32 + f]) << 16);
        acc += h0 + h1 + h2 + h3;
    }
    for (; i < e; i += 2) {
        int s0 = __builtin_nontemporal_load(&col[i]);
        acc += __uint_as_float(((uint32)Hb[(size_t)s0 * 32 + f]) << 16);
    }
    acc += __shfl_xor(acc, 32);
    if (!half) out[(size_t)node * 32 + f] = fmaf(dinv[node], acc, bias[f]);
}

// ---- global mean pool over sorted batch ids -------------------------------
__global__ __launch_bounds__(256) void pool_k(const float* __restrict__ h,
                                              const int* __restrict__ batch, int M,
                                              float* __restrict__ out) {
    int g = blockIdx.x;
    int lo, hi;
    {
        int l = 0, r = M;
        while (l < r) { int m = (l + r) >> 1; if (batch[m] < g) l = m + 1; else r = m; }
        lo = l;
    }
    {
        int l = lo, r = M;
        while (l < r) { int m = (l + r) >> 1; if (batch[m] < g + 1) l = m + 1; else r = m; }
        hi = l;
    }
    int f = threadIdx.x & 31;
    int chunk = threadIdx.x >> 5;  // 8 chunks
    float acc = 0.f;
    for (int i = lo + chunk; i < hi; i += 8) acc += h[(size_t)i * 32 + f];
    __shared__ float red[8][32];
    red[chunk][f] = acc;
    __syncthreads();
    if (threadIdx.x < 32) {
        float s = 0.f;
#pragma unroll
        for (int c = 0; c < 8; c++) s += red[c][f];
        out[g * 32 + f] = s / fmaxf((float)(hi - lo), 1.f);
    }
}

extern "C" void kernel_launch(void* const* d_in, const int* in_sizes, int n_in,
                              void* d_out, int out_size, void* d_ws, size_t ws_size,
                              hipStream_t stream) {
    const float* x   = (const float*)d_in[0];
    const int* ei    = (const int*)d_in[1];
    const int* batch = (const int*)d_in[2];
    const float* W1  = (const float*)d_in[4];
    const float* b1  = (const float*)d_in[5];
    const float* W2  = (const float*)d_in[6];
    const float* b2  = (const float*)d_in[7];
    const float* W3  = (const float*)d_in[8];
    const float* b3  = (const float*)d_in[9];

    const int M = in_sizes[0] / 128;
    const int E = in_sizes[1] / 2;
    const int G = 64;  // N_GRAPHS (problem constant)
    const int* srcp = ei;
    const int* dstp = ei + E;

    // workspace carve (256B aligned)
    char* p = (char*)d_ws;
    auto carve = [&](size_t bytes) {
        void* r = (void*)p;
        p += (bytes + 255) & ~(size_t)255;
        return r;
    };
    int*   deg    = (int*)carve((size_t)M * 4);
    float* dinv   = (float*)carve((size_t)M * 4);
    int*   rowptr = (int*)carve((size_t)(M + 1) * 4);
    int*   cursor = (int*)carve((size_t)M * 4);
    int*   blksum = (int*)carve(512 * 4);
    int*   col    = (int*)carve((size_t)E * 4);
    unsigned short* Xs  = (unsigned short*)carve((size_t)M * 128 * 2);  // sliced
    unsigned short* Hs  = (unsigned short*)carve((size_t)M * 128 * 2);  // sliced
    unsigned short* Os  = (unsigned short*)carve((size_t)M * 128 * 2);  // sliced
    unsigned short* H3  = (unsigned short*)carve((size_t)M * 32 * 2);   // row-major
    unsigned short* Wt1 = (unsigned short*)carve(128 * 128 * 2);
    unsigned short* Wt2 = (unsigned short*)carve(128 * 128 * 2);
    unsigned short* Wt3 = (unsigned short*)carve(32 * 128 * 2);

    float* outh = (float*)d_out;             // [M,32]
    float* outg = outh + (size_t)M * 32;     // [G,32]

    const int nbM = (M + 255) / 256;
    const int nbE = (E + 255) / 256;
    const int nstrips = (M + 15) / 16;
    const int gblk = (nstrips + 7) / 8;      // 4 waves/block, ~2 strips/wave
    const int ablk = 8 * ((M + 31) / 32);    // sliced agg grid

    cvt_k<<<(M * 128 / 8 + 255) / 256, 256, 0, stream>>>(x, Xs, M, M * 128 / 8);
    initdeg_k<<<nbM, 256, 0, stream>>>(deg, M);
    count_k<<<nbE, 256, 0, stream>>>(dstp, E, deg);
    mkdinv_k<<<nbM, 256, 0, stream>>>(deg, dinv, M);
    scan1_k<<<nbM, 256, 0, stream>>>(deg, M, blksum);
    scan2_k<<<1, 512, 0, stream>>>(blksum, nbM);
    scan3_k<<<nbM, 256, 0, stream>>>(deg, M, blksum, rowptr, cursor);
    {
        const int nchunk = (E + FILL_CHUNK - 1) / FILL_CHUNK;
        fill_rp_k<<<nchunk * 8, 256, 0, stream>>>(srcp, dstp, E, M, cursor, col);
    }
    wt_k<<<(128 * 128 + 255) / 256, 256, 0, stream>>>(W1, Wt1, 128);
    wt_k<<<(128 * 128 + 255) / 256, 256, 0, stream>>>(W2, Wt2, 128);
    wt_k<<<(32 * 128 + 255) / 256, 256, 0, stream>>>(W3, Wt3, 32);

    // layer 1
    mgemm_k<8, true><<<gblk, 256, 0, stream>>>(Xs, Wt1, dinv, Hs, M, nstrips);
    agg128s_k<<<ablk, 256, 0, stream>>>(Hs, rowptr, col, dinv, b1, Os, M, 1);
    // layer 2
    mgemm_k<8, true><<<gblk, 256, 0, stream>>>(Os, Wt2, dinv, Hs, M, nstrips);
    agg128s_k<<<ablk, 256, 0, stream>>>(Hs, rowptr, col, dinv, b2, Os, M, 1);
    // layer 3
    mgemm_k<2, false><<<gblk, 256, 0, stream>>>(Os, Wt3, dinv, H3, M, nstrips);
    agg32_k<<<(M + 3) / 4, 256, 0, stream>>>(H3, rowptr, col, dinv, b3, outh, M);
    // pool
    pool_k<<<G, 256, 0, stream>>>(outh, batch, M, outg);
}

// Round 9
// 582.276 us; speedup vs baseline: 1.2598x; 1.2598x over previous
//
#include <hip/hip_runtime.h>
#include <hip/hip_bf16.h>

// ---------------------------------------------------------------------------
// SupplyChainGNN: 3-layer GCN (PyG GCNConv semantics) + global mean pool.
//   deg[i] = 1 + indeg(i);  dinv = rsqrt(deg)
//   GEMM (bf16 MFMA) folds dinv into its output: h' = dinv[row]*(A@W) (bf16)
//   agg:  out[i] = dinv[i]*( sum_{e: dst=i} h'[src] + h'[i] ) + b  (+ReLU)
// CSR (by dst) rebuilt on-device every call (workspace is re-poisoned).
//
// R1: fill range-partitioned (blockIdx%8 ~ XCD) -> full-line col[] writes.
// R2: H stored bf16 + 8-deep gather pipelining (wave-per-node agg).
// R3: GEMMs -> mfma_f32_16x16x32_bf16, W frags in VGPRs, A direct-global.
// R5: sliced-h agg + nt-loads + dinv-folded GEMM.
// R8: POST-MORTEM: sliced agg REGRESSED (141us vs ~70; FETCH==payload ->
//     slice NOT L2-resident, and 32B/edge transactions + 4-deep pipe are
//     latency-bound at 0.53TB/s). REVERT agg to R3 wave-per-node row-major
//     (256B/edge, 8-deep); KEEP dinv-folding (no per-edge dinv gather) and
//     nt-loads on streamed col/edge reads.
// ---------------------------------------------------------------------------

typedef unsigned int uint32;
typedef short short8 __attribute__((ext_vector_type(8)));
typedef float f32x4 __attribute__((ext_vector_type(4)));

static __device__ __forceinline__ unsigned short f2bf(float f) {
    uint32 u = __float_as_uint(f);
    return (unsigned short)((u + 0x7fffu + ((u >> 16) & 1u)) >> 16);  // RNE
}
static __device__ __forceinline__ float bf2f_lo(uint32 u) {
    return __uint_as_float(u << 16);
}
static __device__ __forceinline__ float bf2f_hi(uint32 u) {
    return __uint_as_float(u & 0xffff0000u);
}

__global__ __launch_bounds__(256) void initdeg_k(int* deg, int M) {
    int i = blockIdx.x * 256 + threadIdx.x;
    if (i < M) deg[i] = 1;  // self loop
}

__global__ __launch_bounds__(256) void count_k(const int* __restrict__ dst, int E,
                                               int* __restrict__ deg) {
    int e = blockIdx.x * 256 + threadIdx.x;
    if (e < E) atomicAdd(&deg[__builtin_nontemporal_load(&dst[e])], 1);
}

__global__ __launch_bounds__(256) void mkdinv_k(const int* __restrict__ deg,
                                                float* __restrict__ dinv, int M) {
    int i = blockIdx.x * 256 + threadIdx.x;
    if (i < M) dinv[i] = rsqrtf((float)deg[i]);
}

// ---- block-scan of edge counts (deg-1) to build rowptr --------------------
__global__ __launch_bounds__(256) void scan1_k(const int* __restrict__ deg, int M,
                                               int* __restrict__ blksum) {
    __shared__ int sh[256];
    int i = blockIdx.x * 256 + threadIdx.x;
    int v = (i < M) ? deg[i] - 1 : 0;
    sh[threadIdx.x] = v;
    __syncthreads();
    for (int o = 128; o > 0; o >>= 1) {
        if (threadIdx.x < o) sh[threadIdx.x] += sh[threadIdx.x + o];
        __syncthreads();
    }
    if (threadIdx.x == 0) blksum[blockIdx.x] = sh[0];
}

__global__ __launch_bounds__(512) void scan2_k(int* __restrict__ blksum, int nb) {
    __shared__ int sh[512];
    int tid = threadIdx.x;
    int v = (tid < nb) ? blksum[tid] : 0;
    sh[tid] = v;
    __syncthreads();
    for (int o = 1; o < 512; o <<= 1) {
        int t = (tid >= o) ? sh[tid - o] : 0;
        __syncthreads();
        sh[tid] += t;
        __syncthreads();
    }
    if (tid < nb) blksum[tid] = sh[tid] - v;  // exclusive
}

__global__ __launch_bounds__(256) void scan3_k(const int* __restrict__ deg, int M,
                                               const int* __restrict__ blksum,
                                               int* __restrict__ rowptr,
                                               int* __restrict__ cursor) {
    __shared__ int sh[256];
    int tid = threadIdx.x;
    int i = blockIdx.x * 256 + tid;
    int v = (i < M) ? deg[i] - 1 : 0;
    sh[tid] = v;
    __syncthreads();
    for (int o = 1; o < 256; o <<= 1) {
        int t = (tid >= o) ? sh[tid - o] : 0;
        __syncthreads();
        sh[tid] += t;
        __syncthreads();
    }
    int excl = sh[tid] - v + blksum[blockIdx.x];
    if (i < M) {
        rowptr[i] = excl;
        cursor[i] = excl;
    }
    if (i == M - 1) rowptr[M] = excl + v;
}

// ---- CSR slot fill, dst-range partitioned; nt edge reads ------------------
#define FILL_CHUNK 4096
__global__ __launch_bounds__(256) void fill_rp_k(const int* __restrict__ src,
                                                 const int* __restrict__ dst,
                                                 int E, int M,
                                                 int* __restrict__ cursor,
                                                 int* __restrict__ col) {
    const int r = blockIdx.x & 7;
    const int chunk = blockIdx.x >> 3;
    const int lo = (int)(((long long)r * M) >> 3);
    const int hi = (int)(((long long)(r + 1) * M) >> 3);
    const int base = chunk * FILL_CHUNK;
    const int end = min(E, base + FILL_CHUNK);
    for (int e = base + (int)threadIdx.x; e < end; e += 256) {
        int d = __builtin_nontemporal_load(&dst[e]);
        int s = __builtin_nontemporal_load(&src[e]);
        if (d >= lo && d < hi) {
            int slot = atomicAdd(&cursor[d], 1);
            col[slot] = s;
        }
    }
}

// ---- f32 -> bf16 convert (x input), row-major, 8 elems/thread -------------
__global__ __launch_bounds__(256) void cvt_k(const float* __restrict__ x,
                                             unsigned short* __restrict__ o,
                                             int n8) {
    int i = blockIdx.x * 256 + threadIdx.x;
    if (i >= n8) return;
    const float4* xp = (const float4*)x + (size_t)i * 2;
    float4 a = xp[0], b = xp[1];
    union { unsigned short us[8]; uint4 v; } u;
    u.us[0] = f2bf(a.x); u.us[1] = f2bf(a.y); u.us[2] = f2bf(a.z); u.us[3] = f2bf(a.w);
    u.us[4] = f2bf(b.x); u.us[5] = f2bf(b.y); u.us[6] = f2bf(b.z); u.us[7] = f2bf(b.w);
    *((uint4*)o + i) = u.v;
}

// ---- W[128][N] f32 -> Wt[N][128] bf16 (transpose + convert) ---------------
__global__ __launch_bounds__(256) void wt_k(const float* __restrict__ W,
                                            unsigned short* __restrict__ Wt,
                                            int N) {
    int idx = blockIdx.x * 256 + threadIdx.x;
    if (idx >= N * 128) return;
    int n = idx >> 7, k = idx & 127;
    Wt[idx] = f2bf(W[k * N + n]);
}

// ---- MFMA GEMM: C[M,N](bf16) = dinv[row] * (A[M,128](bf16) @ W) -----------
// W given as Wt[N][128]. frag: lane r=l&15 (row/col), g=l>>4 (k-group);
// A/B elem j of (g,s) <-> k = 32s+8g+j (consistent pairing => exact).
// C/D (m89-verified): col = l&15, row = 4*(l>>4) + reg.
template <int NT>  // NT 16-col tiles; N = 16*NT
__global__ __launch_bounds__(256) void mgemm_k(const unsigned short* __restrict__ A,
                                               const unsigned short* __restrict__ Wt,
                                               const float* __restrict__ dinv,
                                               unsigned short* __restrict__ C,
                                               int M, int nstrips) {
    constexpr int N = NT * 16;
    const int lane = threadIdx.x & 63;
    const int wid = threadIdx.x >> 6;
    const int r = lane & 15;
    const int g = lane >> 4;

    short8 wf[NT][4];
#pragma unroll
    for (int t = 0; t < NT; t++)
#pragma unroll
        for (int s = 0; s < 4; s++)
            wf[t][s] = *(const short8*)&Wt[(size_t)(t * 16 + r) * 128 + s * 32 + g * 8];

    const int stride = gridDim.x * 4;
    for (int strip = blockIdx.x * 4 + wid; strip < nstrips; strip += stride) {
        const int R = strip * 16;
        const int ar = min(R + r, M - 1);
        short8 af[4];
#pragma unroll
        for (int s = 0; s < 4; s++)
            af[s] = *(const short8*)&A[(size_t)ar * 128 + s * 32 + g * 8];
        f32x4 acc[NT];
#pragma unroll
        for (int t = 0; t < NT; t++) acc[t] = (f32x4){0.f, 0.f, 0.f, 0.f};
#pragma unroll
        for (int s = 0; s < 4; s++)
#pragma unroll
            for (int t = 0; t < NT; t++)
                acc[t] = __builtin_amdgcn_mfma_f32_16x16x32_bf16(
                    af[s], wf[t][s], acc[t], 0, 0, 0);
#pragma unroll
        for (int j = 0; j < 4; j++) {
            int row = R + 4 * g + j;
            if (row < M) {
                float dv = dinv[row];
#pragma unroll
                for (int t = 0; t < NT; t++)
                    C[(size_t)row * N + t * 16 + r] = f2bf(dv * acc[t][j]);
            }
        }
    }
}

// ---- aggregation, F=128 (bf16 h' row-major): wave/node, 8-deep gathers ----
// h' already scaled by dinv[src]; inner loop is pure adds (no dinv gather).
__global__ __launch_bounds__(256) void agg128_k(const unsigned short* __restrict__ Hb,
                                                const int* __restrict__ rowptr,
                                                const int* __restrict__ col,
                                                const float* __restrict__ dinv,
                                                const float* __restrict__ bias,
                                                unsigned short* __restrict__ outb,
                                                int M, int relu) {
    int node = blockIdx.x * 4 + (threadIdx.x >> 6);
    if (node >= M) return;
    int lane = threadIdx.x & 63;
    const uint32* Hu = (const uint32*)Hb;  // row = 64 uints (128 bf16)
    uint32 su = Hu[(size_t)node * 64 + lane];
    float ax = bf2f_lo(su);   // self term (h' includes dinv factor)
    float ay = bf2f_hi(su);
    const int s = rowptr[node], e = rowptr[node + 1];

    for (int base = s; base < e; base += 64) {
        int n = e - base;
        if (n > 64) n = 64;
        int cid = __builtin_nontemporal_load(&col[base + (lane < n ? lane : 0)]);
        int j = 0;
        for (; j + 8 <= n; j += 8) {
            int sj[8]; uint32 u[8];
#pragma unroll
            for (int k = 0; k < 8; k++) sj[k] = __shfl(cid, j + k);
#pragma unroll
            for (int k = 0; k < 8; k++) u[k] = Hu[(size_t)sj[k] * 64 + lane];
#pragma unroll
            for (int k = 0; k < 8; k++) {
                ax += bf2f_lo(u[k]);
                ay += bf2f_hi(u[k]);
            }
        }
        for (; j < n; j++) {
            int s0 = __shfl(cid, j);
            uint32 u0 = Hu[(size_t)s0 * 64 + lane];
            ax += bf2f_lo(u0);
            ay += bf2f_hi(u0);
        }
    }
    float dv = dinv[node];
    float2 bv = *(const float2*)&bias[lane * 2];
    float ox = fmaf(dv, ax, bv.x), oy = fmaf(dv, ay, bv.y);
    if (relu) { ox = fmaxf(ox, 0.f); oy = fmaxf(oy, 0.f); }
    uint32 pk = (uint32)f2bf(ox) | ((uint32)f2bf(oy) << 16);
    *(uint32*)&outb[(size_t)node * 128 + lane * 2] = pk;
}

// ---- aggregation, F=32 (h' bf16 row-major [M,32]) -> f32 out --------------
__global__ __launch_bounds__(256) void agg32_k(const unsigned short* __restrict__ Hb,
                                               const int* __restrict__ rowptr,
                                               const int* __restrict__ col,
                                               const float* __restrict__ dinv,
                                               const float* __restrict__ bias,
                                               float* __restrict__ out, int M) {
    int node = blockIdx.x * 4 + (threadIdx.x >> 6);
    if (node >= M) return;
    int lane = threadIdx.x & 63;
    int f = lane & 31;
    int half = lane >> 5;
    float acc = 0.f;
    if (!half)
        acc = __uint_as_float(((uint32)Hb[(size_t)node * 32 + f]) << 16);  // self
    const int s = rowptr[node], e = rowptr[node + 1];
    int i = s + half;
    for (; i + 6 < e; i += 8) {
        int s0 = __builtin_nontemporal_load(&col[i]);
        int s1 = __builtin_nontemporal_load(&col[i + 2]);
        int s2 = __builtin_nontemporal_load(&col[i + 4]);
        int s3 = __builtin_nontemporal_load(&col[i + 6]);
        float h0 = __uint_as_float(((uint32)Hb[(size_t)s0 * 32 + f]) << 16);
        float h1 = __uint_as_float(((uint32)Hb[(size_t)s1 * 32 + f]) << 16);
        float h2 = __uint_as_float(((uint32)Hb[(size_t)s2 * 32 + f]) << 16);
        float h3 = __uint_as_float(((uint32)Hb[(size_t)s3 * 32 + f]) << 16);
        acc += h0 + h1 + h2 + h3;
    }
    for (; i < e; i += 2) {
        int s0 = __builtin_nontemporal_load(&col[i]);
        acc += __uint_as_float(((uint32)Hb[(size_t)s0 * 32 + f]) << 16);
    }
    acc += __shfl_xor(acc, 32);
    if (!half) out[(size_t)node * 32 + f] = fmaf(dinv[node], acc, bias[f]);
}

// ---- global mean pool over sorted batch ids -------------------------------
__global__ __launch_bounds__(256) void pool_k(const float* __restrict__ h,
                                              const int* __restrict__ batch, int M,
                                              float* __restrict__ out) {
    int g = blockIdx.x;
    int lo, hi;
    {
        int l = 0, r = M;
        while (l < r) { int m = (l + r) >> 1; if (batch[m] < g) l = m + 1; else r = m; }
        lo = l;
    }
    {
        int l = lo, r = M;
        while (l < r) { int m = (l + r) >> 1; if (batch[m] < g + 1) l = m + 1; else r = m; }
        hi = l;
    }
    int f = threadIdx.x & 31;
    int chunk = threadIdx.x >> 5;  // 8 chunks
    float acc = 0.f;
    for (int i = lo + chunk; i < hi; i += 8) acc += h[(size_t)i * 32 + f];
    __shared__ float red[8][32];
    red[chunk][f] = acc;
    __syncthreads();
    if (threadIdx.x < 32) {
        float s = 0.f;
#pragma unroll
        for (int c = 0; c < 8; c++) s += red[c][f];
        out[g * 32 + f] = s / fmaxf((float)(hi - lo), 1.f);
    }
}

extern "C" void kernel_launch(void* const* d_in, const int* in_sizes, int n_in,
                              void* d_out, int out_size, void* d_ws, size_t ws_size,
                              hipStream_t stream) {
    const float* x   = (const float*)d_in[0];
    const int* ei    = (const int*)d_in[1];
    const int* batch = (const int*)d_in[2];
    const float* W1  = (const float*)d_in[4];
    const float* b1  = (const float*)d_in[5];
    const float* W2  = (const float*)d_in[6];
    const float* b2  = (const float*)d_in[7];
    const float* W3  = (const float*)d_in[8];
    const float* b3  = (const float*)d_in[9];

    const int M = in_sizes[0] / 128;
    const int E = in_sizes[1] / 2;
    const int G = 64;  // N_GRAPHS (problem constant)
    const int* srcp = ei;
    const int* dstp = ei + E;

    // workspace carve (256B aligned)
    char* p = (char*)d_ws;
    auto carve = [&](size_t bytes) {
        void* r = (void*)p;
        p += (bytes + 255) & ~(size_t)255;
        return r;
    };
    int*   deg    = (int*)carve((size_t)M * 4);
    float* dinv   = (float*)carve((size_t)M * 4);
    int*   rowptr = (int*)carve((size_t)(M + 1) * 4);
    int*   cursor = (int*)carve((size_t)M * 4);
    int*   blksum = (int*)carve(512 * 4);
    int*   col    = (int*)carve((size_t)E * 4);
    unsigned short* Xb  = (unsigned short*)carve((size_t)M * 128 * 2);
    unsigned short* Hb  = (unsigned short*)carve((size_t)M * 128 * 2);
    unsigned short* Ob  = (unsigned short*)carve((size_t)M * 128 * 2);
    unsigned short* H3  = (unsigned short*)carve((size_t)M * 32 * 2);
    unsigned short* Wt1 = (unsigned short*)carve(128 * 128 * 2);
    unsigned short* Wt2 = (unsigned short*)carve(128 * 128 * 2);
    unsigned short* Wt3 = (unsigned short*)carve(32 * 128 * 2);

    float* outh = (float*)d_out;             // [M,32]
    float* outg = outh + (size_t)M * 32;     // [G,32]

    const int nbM = (M + 255) / 256;
    const int nbE = (E + 255) / 256;
    const int nstrips = (M + 15) / 16;
    const int gblk = (nstrips + 7) / 8;      // 4 waves/block, ~2 strips/wave

    cvt_k<<<(M * 128 / 8 + 255) / 256, 256, 0, stream>>>(x, Xb, M * 128 / 8);
    initdeg_k<<<nbM, 256, 0, stream>>>(deg, M);
    count_k<<<nbE, 256, 0, stream>>>(dstp, E, deg);
    mkdinv_k<<<nbM, 256, 0, stream>>>(deg, dinv, M);
    scan1_k<<<nbM, 256, 0, stream>>>(deg, M, blksum);
    scan2_k<<<1, 512, 0, stream>>>(blksum, nbM);
    scan3_k<<<nbM, 256, 0, stream>>>(deg, M, blksum, rowptr, cursor);
    {
        const int nchunk = (E + FILL_CHUNK - 1) / FILL_CHUNK;
        fill_rp_k<<<nchunk * 8, 256, 0, stream>>>(srcp, dstp, E, M, cursor, col);
    }
    wt_k<<<(128 * 128 + 255) / 256, 256, 0, stream>>>(W1, Wt1, 128);
    wt_k<<<(128 * 128 + 255) / 256, 256, 0, stream>>>(W2, Wt2, 128);
    wt_k<<<(32 * 128 + 255) / 256, 256, 0, stream>>>(W3, Wt3, 32);

    // layer 1
    mgemm_k<8><<<gblk, 256, 0, stream>>>(Xb, Wt1, dinv, Hb, M, nstrips);
    agg128_k<<<(M + 3) / 4, 256, 0, stream>>>(Hb, rowptr, col, dinv, b1, Ob, M, 1);
    // layer 2
    mgemm_k<8><<<gblk, 256, 0, stream>>>(Ob, Wt2, dinv, Hb, M, nstrips);
    agg128_k<<<(M + 3) / 4, 256, 0, stream>>>(Hb, rowptr, col, dinv, b2, Ob, M, 1);
    // layer 3
    mgemm_k<2><<<gblk, 256, 0, stream>>>(Ob, Wt3, dinv, H3, M, nstrips);
    agg32_k<<<(M + 3) / 4, 256, 0, stream>>>(H3, rowptr, col, dinv, b3, outh, M);
    // pool
    pool_k<<<G, 256, 0, stream>>>(outh, batch, M, outg);
}

// Round 12
// 536.359 us; speedup vs baseline: 1.3677x; 1.0856x over previous
//
#include <hip/hip_runtime.h>
#include <hip/hip_bf16.h>

// ---------------------------------------------------------------------------
// SupplyChainGNN: 3-layer GCN (PyG GCNConv semantics) + global mean pool.
//   deg[i] = 1 + indeg(i);  dinv = rsqrt(deg)
//   GEMM (bf16 MFMA) folds dinv into its output: h' = dinv[row]*(A@W) (bf16)
//   agg:  out[i] = dinv[i]*( sum_{e: dst=i} h'[src] + h'[i] ) + b  (+ReLU)
// CSR (by dst) rebuilt on-device every call (workspace is re-poisoned).
//
// R2: H stored bf16 + 8-deep gather pipelining (wave-per-node agg).
// R3: GEMMs -> mfma_f32_16x16x32_bf16, W frags in VGPRs, A direct-global.
// R8: dinv folded into GEMM epilogue (no per-edge dinv gather).
// R9: CSR build -> two-level counting sort (bucket = 128 dst nodes; FIFO
//     binning with LDS-reserved ranges; per-bucket scatter into L1-hot 8KB
//     col windows -> temporal locality by construction; bdeg_k LDS histogram
//     replaces count_k's global atomics).
// R10/R11: identical resubmits (container failure / acquisition timeout).
// ---------------------------------------------------------------------------

typedef unsigned int uint32;
typedef short short8 __attribute__((ext_vector_type(8)));
typedef float f32x4 __attribute__((ext_vector_type(4)));

#define BSH 7                    // bucket shift: 128 nodes/bucket
#define MAXB 1024                // supports M <= 131072
#define BCH 8192                 // edges per binning block

static __device__ __forceinline__ unsigned short f2bf(float f) {
    uint32 u = __float_as_uint(f);
    return (unsigned short)((u + 0x7fffu + ((u >> 16) & 1u)) >> 16);  // RNE
}
static __device__ __forceinline__ float bf2f_lo(uint32 u) {
    return __uint_as_float(u << 16);
}
static __device__ __forceinline__ float bf2f_hi(uint32 u) {
    return __uint_as_float(u & 0xffff0000u);
}

// ---- zero the bucket counters --------------------------------------------
__global__ __launch_bounds__(256) void zcnt_k(int* bcnt) {
    bcnt[blockIdx.x * 256 + threadIdx.x] = 0;
}

// ---- per-bucket edge histogram (LDS-aggregated) ---------------------------
__global__ __launch_bounds__(256) void bhist_k(const int* __restrict__ dst, int E,
                                               int* __restrict__ bcnt) {
    __shared__ int h[MAXB];
    for (int i = threadIdx.x; i < MAXB; i += 256) h[i] = 0;
    __syncthreads();
    const int base = blockIdx.x * BCH;
    const int end = min(E, base + BCH);
    for (int e = base + (int)threadIdx.x; e < end; e += 256)
        atomicAdd(&h[__builtin_nontemporal_load(&dst[e]) >> BSH], 1);
    __syncthreads();
    for (int i = threadIdx.x; i < MAXB; i += 256)
        if (h[i]) atomicAdd(&bcnt[i], h[i]);
}

// ---- exclusive scan of bucket counts (1 block, 4 elems/thread) ------------
__global__ __launch_bounds__(256) void bscan_k(const int* __restrict__ bcnt,
                                               int* __restrict__ bstart,
                                               int* __restrict__ bcur, int B) {
    __shared__ int tot[256];
    const int tid = threadIdx.x;
    int v[4];
    int s = 0;
#pragma unroll
    for (int j = 0; j < 4; j++) {
        int idx = tid * 4 + j;
        v[j] = (idx < B) ? bcnt[idx] : 0;
        s += v[j];
    }
    tot[tid] = s;
    __syncthreads();
    for (int o = 1; o < 256; o <<= 1) {
        int t = (tid >= o) ? tot[tid - o] : 0;
        __syncthreads();
        tot[tid] += t;
        __syncthreads();
    }
    int run = tot[tid] - s;  // exclusive
#pragma unroll
    for (int j = 0; j < 4; j++) {
        int idx = tid * 4 + j;
        if (idx < B) {
            bstart[idx] = run;
            bcur[idx] = run;
            run += v[j];
        }
    }
    if (tid == 255) bstart[B] = run;  // total (v[j]=0 past B)
}

// ---- bin edges into bucket-ordered FIFO (packed: src | dlocal<<20) --------
__global__ __launch_bounds__(256) void bfill_k(const int* __restrict__ src,
                                               const int* __restrict__ dst, int E,
                                               int* __restrict__ bcur,
                                               int* __restrict__ fifo) {
    __shared__ int h[MAXB];
    __shared__ int base[MAXB];
    for (int i = threadIdx.x; i < MAXB; i += 256) h[i] = 0;
    __syncthreads();
    const int b0 = blockIdx.x * BCH;
    const int end = min(E, b0 + BCH);
    for (int e = b0 + (int)threadIdx.x; e < end; e += 256)
        atomicAdd(&h[__builtin_nontemporal_load(&dst[e]) >> BSH], 1);
    __syncthreads();
    for (int i = threadIdx.x; i < MAXB; i += 256) {
        int c = h[i];
        base[i] = c ? atomicAdd(&bcur[i], c) : 0;
        h[i] = 0;  // reuse as local cursor
    }
    __syncthreads();
    for (int e = b0 + (int)threadIdx.x; e < end; e += 256) {
        int d = __builtin_nontemporal_load(&dst[e]);
        int s = __builtin_nontemporal_load(&src[e]);
        int b = d >> BSH;
        int off = base[b] + atomicAdd(&h[b], 1);
        fifo[off] = s | ((d & 127) << 20);
    }
}

// ---- per-bucket degree count (LDS histogram, zero global atomics) ---------
__global__ __launch_bounds__(256) void bdeg_k(const int* __restrict__ fifo,
                                              const int* __restrict__ bstart,
                                              int* __restrict__ deg, int M) {
    __shared__ int h[128];
    const int t = threadIdx.x;
    if (t < 128) h[t] = 0;
    __syncthreads();
    const int lo = bstart[blockIdx.x], hi = bstart[blockIdx.x + 1];
    for (int i = lo + t; i < hi; i += 256)
        atomicAdd(&h[fifo[i] >> 20], 1);
    __syncthreads();
    int node = (blockIdx.x << BSH) + t;
    if (t < 128 && node < M) deg[node] = 1 + h[t];  // +1 self loop
}

__global__ __launch_bounds__(256) void mkdinv_k(const int* __restrict__ deg,
                                                float* __restrict__ dinv, int M) {
    int i = blockIdx.x * 256 + threadIdx.x;
    if (i < M) dinv[i] = rsqrtf((float)deg[i]);
}

// ---- block-scan of edge counts (deg-1) to build rowptr --------------------
__global__ __launch_bounds__(256) void scan1_k(const int* __restrict__ deg, int M,
                                               int* __restrict__ blksum) {
    __shared__ int sh[256];
    int i = blockIdx.x * 256 + threadIdx.x;
    int v = (i < M) ? deg[i] - 1 : 0;
    sh[threadIdx.x] = v;
    __syncthreads();
    for (int o = 128; o > 0; o >>= 1) {
        if (threadIdx.x < o) sh[threadIdx.x] += sh[threadIdx.x + o];
        __syncthreads();
    }
    if (threadIdx.x == 0) blksum[blockIdx.x] = sh[0];
}

__global__ __launch_bounds__(512) void scan2_k(int* __restrict__ blksum, int nb) {
    __shared__ int sh[512];
    int tid = threadIdx.x;
    int v = (tid < nb) ? blksum[tid] : 0;
    sh[tid] = v;
    __syncthreads();
    for (int o = 1; o < 512; o <<= 1) {
        int t = (tid >= o) ? sh[tid - o] : 0;
        __syncthreads();
        sh[tid] += t;
        __syncthreads();
    }
    if (tid < nb) blksum[tid] = sh[tid] - v;  // exclusive
}

__global__ __launch_bounds__(256) void scan3_k(const int* __restrict__ deg, int M,
                                               const int* __restrict__ blksum,
                                               int* __restrict__ rowptr,
                                               int* __restrict__ cursor) {
    __shared__ int sh[256];
    int tid = threadIdx.x;
    int i = blockIdx.x * 256 + tid;
    int v = (i < M) ? deg[i] - 1 : 0;
    sh[tid] = v;
    __syncthreads();
    for (int o = 1; o < 256; o <<= 1) {
        int t = (tid >= o) ? sh[tid - o] : 0;
        __syncthreads();
        sh[tid] += t;
        __syncthreads();
    }
    int excl = sh[tid] - v + blksum[blockIdx.x];
    if (i < M) {
        rowptr[i] = excl;
        cursor[i] = excl;
    }
    if (i == M - 1) rowptr[M] = excl + v;
}

// ---- per-bucket CSR col fill: L1-hot 8KB window, full-line merging --------
__global__ __launch_bounds__(256) void bcol_k(const int* __restrict__ fifo,
                                              const int* __restrict__ bstart,
                                              int* __restrict__ cursor,
                                              int* __restrict__ col) {
    const int lo = bstart[blockIdx.x], hi = bstart[blockIdx.x + 1];
    const int nbase = blockIdx.x << BSH;
    for (int i = lo + (int)threadIdx.x; i < hi; i += 256) {
        int ev = fifo[i];
        int node = nbase + (ev >> 20);
        int slot = atomicAdd(&cursor[node], 1);
        col[slot] = ev & 0xFFFFF;
    }
}

// ---- f32 -> bf16 convert (x input), row-major, 8 elems/thread -------------
__global__ __launch_bounds__(256) void cvt_k(const float* __restrict__ x,
                                             unsigned short* __restrict__ o,
                                             int n8) {
    int i = blockIdx.x * 256 + threadIdx.x;
    if (i >= n8) return;
    const float4* xp = (const float4*)x + (size_t)i * 2;
    float4 a = xp[0], b = xp[1];
    union { unsigned short us[8]; uint4 v; } u;
    u.us[0] = f2bf(a.x); u.us[1] = f2bf(a.y); u.us[2] = f2bf(a.z); u.us[3] = f2bf(a.w);
    u.us[4] = f2bf(b.x); u.us[5] = f2bf(b.y); u.us[6] = f2bf(b.z); u.us[7] = f2bf(b.w);
    *((uint4*)o + i) = u.v;
}

// ---- W[128][N] f32 -> Wt[N][128] bf16 (transpose + convert) ---------------
__global__ __launch_bounds__(256) void wt_k(const float* __restrict__ W,
                                            unsigned short* __restrict__ Wt,
                                            int N) {
    int idx = blockIdx.x * 256 + threadIdx.x;
    if (idx >= N * 128) return;
    int n = idx >> 7, k = idx & 127;
    Wt[idx] = f2bf(W[k * N + n]);
}

// ---- MFMA GEMM: C[M,N](bf16) = dinv[row] * (A[M,128](bf16) @ W) -----------
// W given as Wt[N][128]. frag: lane r=l&15 (row/col), g=l>>4 (k-group);
// A/B elem j of (g,s) <-> k = 32s+8g+j (consistent pairing => exact).
// C/D (m89-verified): col = l&15, row = 4*(l>>4) + reg.
template <int NT>  // NT 16-col tiles; N = 16*NT
__global__ __launch_bounds__(256) void mgemm_k(const unsigned short* __restrict__ A,
                                               const unsigned short* __restrict__ Wt,
                                               const float* __restrict__ dinv,
                                               unsigned short* __restrict__ C,
                                               int M, int nstrips) {
    constexpr int N = NT * 16;
    const int lane = threadIdx.x & 63;
    const int wid = threadIdx.x >> 6;
    const int r = lane & 15;
    const int g = lane >> 4;

    short8 wf[NT][4];
#pragma unroll
    for (int t = 0; t < NT; t++)
#pragma unroll
        for (int s = 0; s < 4; s++)
            wf[t][s] = *(const short8*)&Wt[(size_t)(t * 16 + r) * 128 + s * 32 + g * 8];

    const int stride = gridDim.x * 4;
    for (int strip = blockIdx.x * 4 + wid; strip < nstrips; strip += stride) {
        const int R = strip * 16;
        const int ar = min(R + r, M - 1);
        short8 af[4];
#pragma unroll
        for (int s = 0; s < 4; s++)
            af[s] = *(const short8*)&A[(size_t)ar * 128 + s * 32 + g * 8];
        f32x4 acc[NT];
#pragma unroll
        for (int t = 0; t < NT; t++) acc[t] = (f32x4){0.f, 0.f, 0.f, 0.f};
#pragma unroll
        for (int s = 0; s < 4; s++)
#pragma unroll
            for (int t = 0; t < NT; t++)
                acc[t] = __builtin_amdgcn_mfma_f32_16x16x32_bf16(
                    af[s], wf[t][s], acc[t], 0, 0, 0);
#pragma unroll
        for (int j = 0; j < 4; j++) {
            int row = R + 4 * g + j;
            if (row < M) {
                float dv = dinv[row];
#pragma unroll
                for (int t = 0; t < NT; t++)
                    C[(size_t)row * N + t * 16 + r] = f2bf(dv * acc[t][j]);
            }
        }
    }
}

// ---- aggregation, F=128 (bf16 h' row-major): wave/node, 8-deep gathers ----
__global__ __launch_bounds__(256) void agg128_k(const unsigned short* __restrict__ Hb,
                                                const int* __restrict__ rowptr,
                                                const int* __restrict__ col,
                                                const float* __restrict__ dinv,
                                                const float* __restrict__ bias,
                                                unsigned short* __restrict__ outb,
                                                int M, int relu) {
    int node = blockIdx.x * 4 + (threadIdx.x >> 6);
    if (node >= M) return;
    int lane = threadIdx.x & 63;
    const uint32* Hu = (const uint32*)Hb;  // row = 64 uints (128 bf16)
    uint32 su = Hu[(size_t)node * 64 + lane];
    float ax = bf2f_lo(su);   // self term (h' includes dinv factor)
    float ay = bf2f_hi(su);
    const int s = rowptr[node], e = rowptr[node + 1];

    for (int base = s; base < e; base += 64) {
        int n = e - base;
        if (n > 64) n = 64;
        int cid = __builtin_nontemporal_load(&col[base + (lane < n ? lane : 0)]);
        int j = 0;
        for (; j + 8 <= n; j += 8) {
            int sj[8]; uint32 u[8];
#pragma unroll
            for (int k = 0; k < 8; k++) sj[k] = __shfl(cid, j + k);
#pragma unroll
            for (int k = 0; k < 8; k++) u[k] = Hu[(size_t)sj[k] * 64 + lane];
#pragma unroll
            for (int k = 0; k < 8; k++) {
                ax += bf2f_lo(u[k]);
                ay += bf2f_hi(u[k]);
            }
        }
        for (; j < n; j++) {
            int s0 = __shfl(cid, j);
            uint32 u0 = Hu[(size_t)s0 * 64 + lane];
            ax += bf2f_lo(u0);
            ay += bf2f_hi(u0);
        }
    }
    float dv = dinv[node];
    float2 bv = *(const float2*)&bias[lane * 2];
    float ox = fmaf(dv, ax, bv.x), oy = fmaf(dv, ay, bv.y);
    if (relu) { ox = fmaxf(ox, 0.f); oy = fmaxf(oy, 0.f); }
    uint32 pk = (uint32)f2bf(ox) | ((uint32)f2bf(oy) << 16);
    *(uint32*)&outb[(size_t)node * 128 + lane * 2] = pk;
}

// ---- aggregation, F=32 (h' bf16 row-major [M,32]) -> f32 out --------------
__global__ __launch_bounds__(256) void agg32_k(const unsigned short* __restrict__ Hb,
                                               const int* __restrict__ rowptr,
                                               const int* __restrict__ col,
                                               const float* __restrict__ dinv,
                                               const float* __restrict__ bias,
                                               float* __restrict__ out, int M) {
    int node = blockIdx.x * 4 + (threadIdx.x >> 6);
    if (node >= M) return;
    int lane = threadIdx.x & 63;
    int f = lane & 31;
    int half = lane >> 5;
    float acc = 0.f;
    if (!half)
        acc = __uint_as_float(((uint32)Hb[(size_t)node * 32 + f]) << 16);  // self
    const int s = rowptr[node], e = rowptr[node + 1];
    int i = s + half;
    for (; i + 6 < e; i += 8) {
        int s0 = __builtin_nontemporal_load(&col[i]);
        int s1 = __builtin_nontemporal_load(&col[i + 2]);
        int s2 = __builtin_nontemporal_load(&col[i + 4]);
        int s3 = __builtin_nontemporal_load(&col[i + 6]);
        float h0 = __uint_as_float(((uint32)Hb[(size_t)s0 * 32 + f]) << 16);
        float h1 = __uint_as_float(((uint32)Hb[(size_t)s1 * 32 + f]) << 16);
        float h2 = __uint_as_float(((uint32)Hb[(size_t)s2 * 32 + f]) << 16);
        float h3 = __uint_as_float(((uint32)Hb[(size_t)s3 * 32 + f]) << 16);
        acc += h0 + h1 + h2 + h3;
    }
    for (; i < e; i += 2) {
        int s0 = __builtin_nontemporal_load(&col[i]);
        acc += __uint_as_float(((uint32)Hb[(size_t)s0 * 32 + f]) << 16);
    }
    acc += __shfl_xor(acc, 32);
    if (!half) out[(size_t)node * 32 + f] = fmaf(dinv[node], acc, bias[f]);
}

// ---- global mean pool over sorted batch ids -------------------------------
__global__ __launch_bounds__(256) void pool_k(const float* __restrict__ h,
                                              const int* __restrict__ batch, int M,
                                              float* __restrict__ out) {
    int g = blockIdx.x;
    int lo, hi;
    {
        int l = 0, r = M;
        while (l < r) { int m = (l + r) >> 1; if (batch[m] < g) l = m + 1; else r = m; }
        lo = l;
    }
    {
        int l = lo, r = M;
        while (l < r) { int m = (l + r) >> 1; if (batch[m] < g + 1) l = m + 1; else r = m; }
        hi = l;
    }
    int f = threadIdx.x & 31;
    int chunk = threadIdx.x >> 5;  // 8 chunks
    float acc = 0.f;
    for (int i = lo + chunk; i < hi; i += 8) acc += h[(size_t)i * 32 + f];
    __shared__ float red[8][32];
    red[chunk][f] = acc;
    __syncthreads();
    if (threadIdx.x < 32) {
        float s = 0.f;
#pragma unroll
        for (int c = 0; c < 8; c++) s += red[c][f];
        out[g * 32 + f] = s / fmaxf((float)(hi - lo), 1.f);
    }
}

extern "C" void kernel_launch(void* const* d_in, const int* in_sizes, int n_in,
                              void* d_out, int out_size, void* d_ws, size_t ws_size,
                              hipStream_t stream) {
    const float* x   = (const float*)d_in[0];
    const int* ei    = (const int*)d_in[1];
    const int* batch = (const int*)d_in[2];
    const float* W1  = (const float*)d_in[4];
    const float* b1  = (const float*)d_in[5];
    const float* W2  = (const float*)d_in[6];
    const float* b2  = (const float*)d_in[7];
    const float* W3  = (const float*)d_in[8];
    const float* b3  = (const float*)d_in[9];

    const int M = in_sizes[0] / 128;
    const int E = in_sizes[1] / 2;
    const int G = 64;  // N_GRAPHS (problem constant)
    const int* srcp = ei;
    const int* dstp = ei + E;
    const int B = (M + 127) >> BSH;  // buckets of 128 nodes (B <= MAXB)

    // workspace carve (256B aligned)
    char* p = (char*)d_ws;
    auto carve = [&](size_t bytes) {
        void* r = (void*)p;
        p += (bytes + 255) & ~(size_t)255;
        return r;
    };
    int*   deg    = (int*)carve((size_t)M * 4);
    float* dinv   = (float*)carve((size_t)M * 4);
    int*   rowptr = (int*)carve((size_t)(M + 1) * 4);
    int*   cursor = (int*)carve((size_t)M * 4);
    int*   blksum = (int*)carve(512 * 4);
    int*   bcnt   = (int*)carve(MAXB * 4);
    int*   bstart = (int*)carve((MAXB + 1) * 4);
    int*   bcur   = (int*)carve(MAXB * 4);
    int*   fifo   = (int*)carve((size_t)E * 4);
    int*   col    = (int*)carve((size_t)E * 4);
    unsigned short* Xb  = (unsigned short*)carve((size_t)M * 128 * 2);
    unsigned short* Hb  = (unsigned short*)carve((size_t)M * 128 * 2);
    unsigned short* Ob  = (unsigned short*)carve((size_t)M * 128 * 2);
    unsigned short* H3  = (unsigned short*)carve((size_t)M * 32 * 2);
    unsigned short* Wt1 = (unsigned short*)carve(128 * 128 * 2);
    unsigned short* Wt2 = (unsigned short*)carve(128 * 128 * 2);
    unsigned short* Wt3 = (unsigned short*)carve(32 * 128 * 2);

    float* outh = (float*)d_out;             // [M,32]
    float* outg = outh + (size_t)M * 32;     // [G,32]

    const int nbM = (M + 255) / 256;
    const int nbE = (E + BCH - 1) / BCH;
    const int nstrips = (M + 15) / 16;
    const int gblk = (nstrips + 7) / 8;      // 4 waves/block, ~2 strips/wave

    cvt_k<<<(M * 128 / 8 + 255) / 256, 256, 0, stream>>>(x, Xb, M * 128 / 8);
    // --- CSR build: two-level counting sort ---
    zcnt_k<<<MAXB / 256, 256, 0, stream>>>(bcnt);
    bhist_k<<<nbE, 256, 0, stream>>>(dstp, E, bcnt);
    bscan_k<<<1, 256, 0, stream>>>(bcnt, bstart, bcur, B);
    bfill_k<<<nbE, 256, 0, stream>>>(srcp, dstp, E, bcur, fifo);
    bdeg_k<<<B, 256, 0, stream>>>(fifo, bstart, deg, M);
    mkdinv_k<<<nbM, 256, 0, stream>>>(deg, dinv, M);
    scan1_k<<<nbM, 256, 0, stream>>>(deg, M, blksum);
    scan2_k<<<1, 512, 0, stream>>>(blksum, nbM);
    scan3_k<<<nbM, 256, 0, stream>>>(deg, M, blksum, rowptr, cursor);
    bcol_k<<<B, 256, 0, stream>>>(fifo, bstart, cursor, col);
    // --- weights ---
    wt_k<<<(128 * 128 + 255) / 256, 256, 0, stream>>>(W1, Wt1, 128);
    wt_k<<<(128 * 128 + 255) / 256, 256, 0, stream>>>(W2, Wt2, 128);
    wt_k<<<(32 * 128 + 255) / 256, 256, 0, stream>>>(W3, Wt3, 32);

    // layer 1
    mgemm_k<8><<<gblk, 256, 0, stream>>>(Xb, Wt1, dinv, Hb, M, nstrips);
    agg128_k<<<(M + 3) / 4, 256, 0, stream>>>(Hb, rowptr, col, dinv, b1, Ob, M, 1);
    // layer 2
    mgemm_k<8><<<gblk, 256, 0, stream>>>(Ob, Wt2, dinv, Hb, M, nstrips);
    agg128_k<<<(M + 3) / 4, 256, 0, stream>>>(Hb, rowptr, col, dinv, b2, Ob, M, 1);
    // layer 3
    mgemm_k<2><<<gblk, 256, 0, stream>>>(Ob, Wt3, dinv, H3, M, nstrips);
    agg32_k<<<(M + 3) / 4, 256, 0, stream>>>(H3, rowptr, col, dinv, b3, outh, M);
    // pool
    pool_k<<<G, 256, 0, stream>>>(outh, batch, M, outg);
}